// Round 4
// baseline (85.204 us; speedup 1.0000x reference)
//
#include <hip/hip_runtime.h>

// AdaptivePatcher: B=32 seqs of S=16384 int32 tokens (0..7).
// MIN_PS=1, MAX_PS=8, LOOKAHEAD=4, THRESH=1.2 bits, PAD=0.
//
// Math (verified rounds 2-3, absmax=0):
//  - hi[p] <=> distinct-count of (masked) 4-window >= 3
//  - is_start[j] = hi[j] || ((j - a(j)) % 8 == 0), a(j)=max(last hi < j, 0)
//    (j==0 subsumed: a=0 -> (0-0)%8==0)
//  - size at start j = min(first d in [1,8) with hi[j+d], else 8, S-j)
//
// Round-4: single fused kernel, grid=256 (one block/CU, all co-resident).
// Cross-chunk state via decoupled lookback: each block publishes a summary
// (lastHi, firstHiLocal, internal start count A) with a MAGIC-tagged 64-bit
// agent-scope release store; consumers acquire-poll. A is anchor-independent
// (starts from firstHi onward); the anchor-dependent leading-run count is
// closed-form: #{j in [cs,fh): j==a mod 8} = ceil((fh-a)/8)-ceil((cs-a)/8).
// Block (b,7) publishes ntot -> tail fill + nout; block (0,0) computes cu.
// MAGIC tag 0x5A17 is distinguishable from the 0xAA..A ws poison -> no init.

#define S_LEN 16384
#define BATCH 32
#define NCH 8
#define CHUNK 2048
#define NTH 256
#define PPT 8
#define MAX_PS 8
#define MAGIC 0x5A17ULL

__global__ __launch_bounds__(NTH)
void fused_kernel(const int* __restrict__ tokens,
                  int* __restrict__ patches,   // [B, S, 8]
                  int* __restrict__ offsets,   // [B, S]
                  int* __restrict__ nout,      // [B]
                  int* __restrict__ cu,        // [B+1]
                  unsigned long long* __restrict__ sumPub,   // [B*NCH]
                  unsigned long long* __restrict__ ntotPub)  // [B]
{
    const int blk = blockIdx.x;
    const int b = blk >> 3, c = blk & 7;
    const int t = threadIdx.x;
    const int lane = t & 63, wv = t >> 6;
    const int cs = c * CHUNK;
    const int p = cs + t * PPT;
    const int* __restrict__ seq = tokens + (size_t)b * S_LEN;
    int* __restrict__ pat = patches + (size_t)b * S_LEN * MAX_PS;
    int* __restrict__ off = offsets + (size_t)b * S_LEN;

    __shared__ unsigned char bs[NTH];
    __shared__ unsigned hw[65];          // 64 words chunk bits + 1 word lookahead
    __shared__ int partMax[4], partSum[4], red[8];
    __shared__ int anch_s, base_s, ntot_s;

    // ---- Phase A: hi bits for own chunk ----
    int v[12];
    int4 a4 = *(const int4*)(seq + p);
    int4 b4 = *(const int4*)(seq + p + 4);
    int4 c4 = make_int4(0, 0, 0, 0);
    if (p + 8 < S_LEN) c4 = *(const int4*)(seq + p + 8);
    v[0]=a4.x; v[1]=a4.y; v[2]=a4.z; v[3]=a4.w;
    v[4]=b4.x; v[5]=b4.y; v[6]=b4.z; v[7]=b4.w;
    v[8]=c4.x; v[9]=c4.y; v[10]=c4.z; v[11]=c4.w;

    unsigned hb = 0;
    int llh = -1, ffh = S_LEN;
#pragma unroll
    for (int k = 0; k < PPT; ++k) {
        int j = p + k;
        int nv = min(4, S_LEN - j);
        unsigned m = 0;
#pragma unroll
        for (int i = 0; i < 4; ++i) if (i < nv) m |= 1u << (v[k + i] & 31);
        int h = (__popc(m) >= 3) ? 1 : 0;
        hb |= (unsigned)h << k;
        if (h) { llh = j; if (ffh == S_LEN) ffh = j; }
    }
    bs[t] = (unsigned char)hb;

    // lookahead hi bits for positions [cs+CHUNK, cs+CHUNK+7) (next chunk / 0 at seq end)
    int eh = 0;
    if (t < 7) {
        int j = cs + CHUNK + t;
        if (j < S_LEN) {
            int nv = min(4, S_LEN - j);
            unsigned m = 0;
            for (int i = 0; i < 4; ++i) if (i < nv) m |= 1u << (seq[j + i] & 31);
            eh = (__popc(m) >= 3) ? 1 : 0;
        }
    }
    unsigned long long bal = __ballot(eh);
    if (t == 0) hw[64] = (unsigned)(bal & 0x7f);

    // wave reductions (max llh, min ffh) + exclusive-prefix-max scan of llh
    int mx = llh, mn = ffh;
#pragma unroll
    for (int d = 32; d >= 1; d >>= 1) {
        mx = max(mx, __shfl_down(mx, d));
        mn = min(mn, __shfl_down(mn, d));
    }
    if (lane == 0) { red[wv] = mx; red[4 + wv] = mn; }
    int incl = llh;
#pragma unroll
    for (int d = 1; d < 64; d <<= 1) {
        int u = __shfl_up(incl, d);
        if (lane >= d) incl = max(incl, u);
    }
    if (lane == 63) partMax[wv] = incl;
    __syncthreads();                                    // (1)

    if (t < 64)
        hw[t] = (unsigned)bs[4*t] | ((unsigned)bs[4*t+1] << 8) |
                ((unsigned)bs[4*t+2] << 16) | ((unsigned)bs[4*t+3] << 24);

    int runx = __shfl_up(incl, 1);
    if (lane == 0) runx = -1;
    for (int w = 0; w < wv; ++w) runx = max(runx, partMax[w]);

    // internal start count A (anchor-independent: only j >= firstHi contribute)
    {
        int run = runx, ci = 0;
#pragma unroll
        for (int k = 0; k < PPT; ++k) {
            int j = p + k;
            int h = (hb >> k) & 1;
            int is = h | ((run >= 0) & (((j - run) & 7) == 0));
            ci += is;
            if (h) run = j;
        }
        int s = ci;
#pragma unroll
        for (int d = 32; d >= 1; d >>= 1) s += __shfl_down(s, d);
        if (lane == 0) partSum[wv] = s;
    }
    __syncthreads();                                    // (2)

    if (t == 0) {
        int lastHi = max(max(red[0], red[1]), max(red[2], red[3]));
        int fh     = min(min(red[4], red[5]), min(red[6], red[7]));
        int fhl    = min(fh - cs, CHUNK);
        int A      = partSum[0] + partSum[1] + partSum[2] + partSum[3];
        unsigned long long pk = (MAGIC << 48)
                              | ((unsigned long long)(unsigned)(lastHi + 1) << 32)
                              | ((unsigned long long)(unsigned)fhl << 16)
                              | (unsigned long long)(unsigned)A;
        __hip_atomic_store(&sumPub[blk], pk, __ATOMIC_RELEASE, __HIP_MEMORY_SCOPE_AGENT);
    }

    // ---- Phase B: lookback over predecessor chunks of this sequence ----
    int lh_l = 0, fl_l = 0, A_l = 0;
    if (wv == 0 && lane < c) {
        unsigned long long sv;
        do {
            sv = __hip_atomic_load(&sumPub[b*NCH + lane], __ATOMIC_ACQUIRE, __HIP_MEMORY_SCOPE_AGENT);
        } while ((sv >> 48) != MAGIC);
        lh_l = (int)((sv >> 32) & 0xffff) - 1;
        fl_l = (int)((sv >> 16) & 0xffff);
        A_l  = (int)(sv & 0xffff);
    }
    if (wv == 0) {
        int anchor = -1, base = 0;
        for (int cp = 0; cp < c; ++cp) {
            int lh = __shfl(lh_l, cp);
            int fl = __shfl(fl_l, cp);
            int Ap = __shfl(A_l, cp);
            int lo = cp * CHUNK, hi2 = lo + fl;
            int a = max(anchor, 0);
            base += ((hi2 - a + 7) >> 3) - ((lo - a + 7) >> 3) + Ap;
            if (lh >= 0) anchor = lh;
        }
        if (lane == 0) { anch_s = anchor; base_s = base; }
    }
    __syncthreads();                                    // (3)

    // ---- Phase C: flags, ranks, emit ----
    int run = max(runx, anch_s);
    unsigned fb = 0;
    int cl = 0;
#pragma unroll
    for (int k = 0; k < PPT; ++k) {
        int j = p + k;
        int h = (hb >> k) & 1;
        int a = max(run, 0);
        int is = h | (((j - a) & 7) == 0);
        fb |= (unsigned)is << k;
        cl += is;
        if (h) run = j;
    }
    int sincl = cl;
#pragma unroll
    for (int d = 1; d < 64; d <<= 1) {
        int u = __shfl_up(sincl, d);
        if (lane >= d) sincl += u;
    }
    if (lane == 63) partSum[wv] = sincl;                // reuse (safe: barrier 3 passed)
    __syncthreads();                                    // (4)
    int sexcl = __shfl_up(sincl, 1);
    if (lane == 0) sexcl = 0;
    int r = base_s + sexcl;
    for (int w = 0; w < wv; ++w) r += partSum[w];

    if (c == NCH - 1 && t == 0) {
        int ntot = base_s + partSum[0] + partSum[1] + partSum[2] + partSum[3];
        ntot_s = ntot;
        nout[b] = ntot;
        __hip_atomic_store(&ntotPub[b], (MAGIC << 48) | (unsigned long long)(unsigned)ntot,
                           __ATOMIC_RELEASE, __HIP_MEMORY_SCOPE_AGENT);
    }

#pragma unroll
    for (int k = 0; k < PPT; ++k) {
        if ((fb >> k) & 1u) {
            int j = p + k;
            int lb = t * PPT + k;
            int size = 8;
#pragma unroll
            for (int d = 1; d <= 7; ++d) {
                int bb = lb + d;
                if ((hw[bb >> 5] >> (bb & 31)) & 1u) { size = d; break; }
            }
            size = min(size, S_LEN - j);
            int vals[8];
#pragma unroll
            for (int q = 0; q < 8; ++q) vals[q] = (q < size) ? seq[j + q] : 0;
            off[r] = j;
            int4* dst = (int4*)(pat + (size_t)r * MAX_PS);
            dst[0] = make_int4(vals[0], vals[1], vals[2], vals[3]);
            dst[1] = make_int4(vals[4], vals[5], vals[6], vals[7]);
            ++r;
        }
    }

    __syncthreads();                                    // (5) ntot_s visible
    if (c == NCH - 1) {
        const int4 z = make_int4(0, 0, 0, 0);
        for (int r2 = ntot_s + t; r2 < S_LEN; r2 += NTH) {
            off[r2] = -1;
            int4* dst = (int4*)(pat + (size_t)r2 * MAX_PS);
            dst[0] = z;
            dst[1] = z;
        }
    }

    // ---- cu_seqlens by block (0,0), wave 0 ----
    if (b == 0 && c == 0 && wv == 0) {
        int nv2 = 0;
        if (lane < BATCH) {
            unsigned long long sv;
            do {
                sv = __hip_atomic_load(&ntotPub[lane], __ATOMIC_ACQUIRE, __HIP_MEMORY_SCOPE_AGENT);
            } while ((sv >> 48) != MAGIC);
            nv2 = (int)(sv & 0xffff);
        }
        int sc2 = nv2;
#pragma unroll
        for (int d = 1; d < 32; d <<= 1) {
            int u = __shfl_up(sc2, d);
            if (lane >= d) sc2 += u;
        }
        if (lane < BATCH) cu[lane + 1] = sc2;
        if (lane == 0) cu[0] = 0;
    }
}

extern "C" void kernel_launch(void* const* d_in, const int* in_sizes, int n_in,
                              void* d_out, int out_size, void* d_ws, size_t ws_size,
                              hipStream_t stream)
{
    const int* tokens = (const int*)d_in[0];
    int* out = (int*)d_out;
    // Output layout (int32, return order):
    //   patches [32,16384,8] -> 4,194,304 ; offsets [32,16384] -> 524,288 ;
    //   n [32] ; cu_seqlens [33]
    int* patches = out;
    int* offsets = patches + (size_t)BATCH * S_LEN * MAX_PS;
    int* nout    = offsets + (size_t)BATCH * S_LEN;
    int* cu      = nout + BATCH;

    unsigned long long* sumPub  = (unsigned long long*)d_ws;            // 2 KB
    unsigned long long* ntotPub = sumPub + BATCH * NCH;                 // 256 B

    fused_kernel<<<dim3(BATCH * NCH), dim3(NTH), 0, stream>>>(
        tokens, patches, offsets, nout, cu, sumPub, ntotPub);
}

// Round 5
// 76.566 us; speedup vs baseline: 1.1128x; 1.1128x over previous
//
#include <hip/hip_runtime.h>

// AdaptivePatcher: B=32 seqs of S=16384 int32 tokens (0..7).
// MIN_PS=1, MAX_PS=8, LOOKAHEAD=4, THRESH=1.2 bits, PAD=0.
//
// Math (verified rounds 2-4, absmax=0):
//  - hi[p] <=> distinct-count of (masked) 4-window >= 3
//  - is_start[j] = hi[j] || ((j - a(j)) % 8 == 0), a(j)=max(last hi < j, 0)
//  - size at start j = min(first d in [1,8) with hi[j+d], else 8, S-j)
//
// Round-5 fix vs round-4: lookback publishes/polls were ACQUIRE/RELEASE at
// agent scope -> on gfx950 (per-XCD L2 NOT the coherence point) every acquire
// poll emitted an L2 INVALIDATE; 224 spinning waves = L2 invalidation storm
// that un-cached concurrent token reads / patch writes (37 us vs 20 us of
// round-3 kernel time). Ordering is not needed: every published 64-bit word
// packs payload WITH the MAGIC tag, so 8-byte store atomicity alone is
// sufficient -> RELAXED everywhere (still agent scope = IF$-visible, but no
// cache-maintenance instructions). s_sleep(1) throttles the polls.

#define S_LEN 16384
#define BATCH 32
#define NCH 8
#define CHUNK 2048
#define NTH 256
#define PPT 8
#define MAX_PS 8
#define MAGIC 0x5A17ULL

__global__ __launch_bounds__(NTH)
void fused_kernel(const int* __restrict__ tokens,
                  int* __restrict__ patches,   // [B, S, 8]
                  int* __restrict__ offsets,   // [B, S]
                  int* __restrict__ nout,      // [B]
                  int* __restrict__ cu,        // [B+1]
                  unsigned long long* __restrict__ sumPub,   // [B*NCH]
                  unsigned long long* __restrict__ ntotPub)  // [B]
{
    const int blk = blockIdx.x;
    const int b = blk >> 3, c = blk & 7;
    const int t = threadIdx.x;
    const int lane = t & 63, wv = t >> 6;
    const int cs = c * CHUNK;
    const int p = cs + t * PPT;
    const int* __restrict__ seq = tokens + (size_t)b * S_LEN;
    int* __restrict__ pat = patches + (size_t)b * S_LEN * MAX_PS;
    int* __restrict__ off = offsets + (size_t)b * S_LEN;

    __shared__ unsigned char bs[NTH];
    __shared__ unsigned hw[65];          // 64 words chunk bits + 1 word lookahead
    __shared__ int partMax[4], partSum[4], red[8];
    __shared__ int anch_s, base_s, ntot_s;

    // ---- Phase A: hi bits for own chunk ----
    int v[12];
    int4 a4 = *(const int4*)(seq + p);
    int4 b4 = *(const int4*)(seq + p + 4);
    int4 c4 = make_int4(0, 0, 0, 0);
    if (p + 8 < S_LEN) c4 = *(const int4*)(seq + p + 8);
    v[0]=a4.x; v[1]=a4.y; v[2]=a4.z; v[3]=a4.w;
    v[4]=b4.x; v[5]=b4.y; v[6]=b4.z; v[7]=b4.w;
    v[8]=c4.x; v[9]=c4.y; v[10]=c4.z; v[11]=c4.w;

    unsigned hb = 0;
    int llh = -1, ffh = S_LEN;
#pragma unroll
    for (int k = 0; k < PPT; ++k) {
        int j = p + k;
        int nv = min(4, S_LEN - j);
        unsigned m = 0;
#pragma unroll
        for (int i = 0; i < 4; ++i) if (i < nv) m |= 1u << (v[k + i] & 31);
        int h = (__popc(m) >= 3) ? 1 : 0;
        hb |= (unsigned)h << k;
        if (h) { llh = j; if (ffh == S_LEN) ffh = j; }
    }
    bs[t] = (unsigned char)hb;

    // lookahead hi bits for positions [cs+CHUNK, cs+CHUNK+7)
    int eh = 0;
    if (t < 7) {
        int j = cs + CHUNK + t;
        if (j < S_LEN) {
            int nv = min(4, S_LEN - j);
            unsigned m = 0;
            for (int i = 0; i < 4; ++i) if (i < nv) m |= 1u << (seq[j + i] & 31);
            eh = (__popc(m) >= 3) ? 1 : 0;
        }
    }
    unsigned long long bal = __ballot(eh);
    if (t == 0) hw[64] = (unsigned)(bal & 0x7f);

    // wave reductions (max llh, min ffh) + exclusive-prefix-max scan of llh
    int mx = llh, mn = ffh;
#pragma unroll
    for (int d = 32; d >= 1; d >>= 1) {
        mx = max(mx, __shfl_down(mx, d));
        mn = min(mn, __shfl_down(mn, d));
    }
    if (lane == 0) { red[wv] = mx; red[4 + wv] = mn; }
    int incl = llh;
#pragma unroll
    for (int d = 1; d < 64; d <<= 1) {
        int u = __shfl_up(incl, d);
        if (lane >= d) incl = max(incl, u);
    }
    if (lane == 63) partMax[wv] = incl;
    __syncthreads();                                    // (1)

    if (t < 64)
        hw[t] = (unsigned)bs[4*t] | ((unsigned)bs[4*t+1] << 8) |
                ((unsigned)bs[4*t+2] << 16) | ((unsigned)bs[4*t+3] << 24);

    int runx = __shfl_up(incl, 1);
    if (lane == 0) runx = -1;
    for (int w = 0; w < wv; ++w) runx = max(runx, partMax[w]);

    // internal start count A (anchor-independent: only j >= firstHi contribute)
    {
        int run = runx, ci = 0;
#pragma unroll
        for (int k = 0; k < PPT; ++k) {
            int j = p + k;
            int h = (hb >> k) & 1;
            int is = h | ((run >= 0) & (((j - run) & 7) == 0));
            ci += is;
            if (h) run = j;
        }
        int s = ci;
#pragma unroll
        for (int d = 32; d >= 1; d >>= 1) s += __shfl_down(s, d);
        if (lane == 0) partSum[wv] = s;
    }
    __syncthreads();                                    // (2)

    if (t == 0) {
        int lastHi = max(max(red[0], red[1]), max(red[2], red[3]));
        int fh     = min(min(red[4], red[5]), min(red[6], red[7]));
        int fhl    = min(fh - cs, CHUNK);
        int A      = partSum[0] + partSum[1] + partSum[2] + partSum[3];
        unsigned long long pk = (MAGIC << 48)
                              | ((unsigned long long)(unsigned)(lastHi + 1) << 32)
                              | ((unsigned long long)(unsigned)fhl << 16)
                              | (unsigned long long)(unsigned)A;
        // payload packed with tag -> RELAXED is sufficient (no L2 writeback)
        __hip_atomic_store(&sumPub[blk], pk, __ATOMIC_RELAXED, __HIP_MEMORY_SCOPE_AGENT);
    }

    // ---- Phase B: lookback over predecessor chunks of this sequence ----
    int lh_l = 0, fl_l = 0, A_l = 0;
    if (wv == 0 && lane < c) {
        unsigned long long sv;
        for (;;) {
            sv = __hip_atomic_load(&sumPub[b*NCH + lane], __ATOMIC_RELAXED, __HIP_MEMORY_SCOPE_AGENT);
            if ((sv >> 48) == MAGIC) break;
            __builtin_amdgcn_s_sleep(1);
        }
        lh_l = (int)((sv >> 32) & 0xffff) - 1;
        fl_l = (int)((sv >> 16) & 0xffff);
        A_l  = (int)(sv & 0xffff);
    }
    if (wv == 0) {
        int anchor = -1, base = 0;
        for (int cp = 0; cp < c; ++cp) {
            int lh = __shfl(lh_l, cp);
            int fl = __shfl(fl_l, cp);
            int Ap = __shfl(A_l, cp);
            int lo = cp * CHUNK, hi2 = lo + fl;
            int a = max(anchor, 0);
            base += ((hi2 - a + 7) >> 3) - ((lo - a + 7) >> 3) + Ap;
            if (lh >= 0) anchor = lh;
        }
        if (lane == 0) { anch_s = anchor; base_s = base; }
    }
    __syncthreads();                                    // (3)

    // ---- Phase C: flags, ranks, emit ----
    int run = max(runx, anch_s);
    unsigned fb = 0;
    int cl = 0;
#pragma unroll
    for (int k = 0; k < PPT; ++k) {
        int j = p + k;
        int h = (hb >> k) & 1;
        int a = max(run, 0);
        int is = h | (((j - a) & 7) == 0);
        fb |= (unsigned)is << k;
        cl += is;
        if (h) run = j;
    }
    int sincl = cl;
#pragma unroll
    for (int d = 1; d < 64; d <<= 1) {
        int u = __shfl_up(sincl, d);
        if (lane >= d) sincl += u;
    }
    if (lane == 63) partSum[wv] = sincl;                // reuse (safe: barrier 3 passed)
    __syncthreads();                                    // (4)
    int sexcl = __shfl_up(sincl, 1);
    if (lane == 0) sexcl = 0;
    int r = base_s + sexcl;
    for (int w = 0; w < wv; ++w) r += partSum[w];

    if (c == NCH - 1 && t == 0) {
        int ntot = base_s + partSum[0] + partSum[1] + partSum[2] + partSum[3];
        ntot_s = ntot;
        nout[b] = ntot;
        __hip_atomic_store(&ntotPub[b], (MAGIC << 48) | (unsigned long long)(unsigned)ntot,
                           __ATOMIC_RELAXED, __HIP_MEMORY_SCOPE_AGENT);
    }

#pragma unroll
    for (int k = 0; k < PPT; ++k) {
        if ((fb >> k) & 1u) {
            int j = p + k;
            int lb = t * PPT + k;
            int size = 8;
#pragma unroll
            for (int d = 1; d <= 7; ++d) {
                int bb = lb + d;
                if ((hw[bb >> 5] >> (bb & 31)) & 1u) { size = d; break; }
            }
            size = min(size, S_LEN - j);
            int vals[8];
#pragma unroll
            for (int q = 0; q < 8; ++q) vals[q] = (q < size) ? seq[j + q] : 0;
            off[r] = j;
            int4* dst = (int4*)(pat + (size_t)r * MAX_PS);
            dst[0] = make_int4(vals[0], vals[1], vals[2], vals[3]);
            dst[1] = make_int4(vals[4], vals[5], vals[6], vals[7]);
            ++r;
        }
    }

    __syncthreads();                                    // (5) ntot_s visible
    if (c == NCH - 1) {
        const int4 z = make_int4(0, 0, 0, 0);
        for (int r2 = ntot_s + t; r2 < S_LEN; r2 += NTH) {
            off[r2] = -1;
            int4* dst = (int4*)(pat + (size_t)r2 * MAX_PS);
            dst[0] = z;
            dst[1] = z;
        }
    }

    // ---- cu_seqlens by block (0,0), wave 0 ----
    if (b == 0 && c == 0 && wv == 0) {
        int nv2 = 0;
        if (lane < BATCH) {
            unsigned long long sv;
            for (;;) {
                sv = __hip_atomic_load(&ntotPub[lane], __ATOMIC_RELAXED, __HIP_MEMORY_SCOPE_AGENT);
                if ((sv >> 48) == MAGIC) break;
                __builtin_amdgcn_s_sleep(1);
            }
            nv2 = (int)(sv & 0xffff);
        }
        int sc2 = nv2;
#pragma unroll
        for (int d = 1; d < 32; d <<= 1) {
            int u = __shfl_up(sc2, d);
            if (lane >= d) sc2 += u;
        }
        if (lane < BATCH) cu[lane + 1] = sc2;
        if (lane == 0) cu[0] = 0;
    }
}

extern "C" void kernel_launch(void* const* d_in, const int* in_sizes, int n_in,
                              void* d_out, int out_size, void* d_ws, size_t ws_size,
                              hipStream_t stream)
{
    const int* tokens = (const int*)d_in[0];
    int* out = (int*)d_out;
    // Output layout (int32, return order):
    //   patches [32,16384,8] -> 4,194,304 ; offsets [32,16384] -> 524,288 ;
    //   n [32] ; cu_seqlens [33]
    int* patches = out;
    int* offsets = patches + (size_t)BATCH * S_LEN * MAX_PS;
    int* nout    = offsets + (size_t)BATCH * S_LEN;
    int* cu      = nout + BATCH;

    unsigned long long* sumPub  = (unsigned long long*)d_ws;            // 2 KB
    unsigned long long* ntotPub = sumPub + BATCH * NCH;                 // 256 B

    fused_kernel<<<dim3(BATCH * NCH), dim3(NTH), 0, stream>>>(
        tokens, patches, offsets, nout, cu, sumPub, ntotPub);
}

// Round 6
// 73.629 us; speedup vs baseline: 1.1572x; 1.0399x over previous
//
#include <hip/hip_runtime.h>

// AdaptivePatcher: B=32 seqs of S=16384 int32 tokens (0..7).
// MIN_PS=1, MAX_PS=8, LOOKAHEAD=4, THRESH=1.2 bits, PAD=0.
//
// Math (verified rounds 2-5, absmax=0):
//  - hi[p] <=> distinct-count of (masked) 4-window >= 3
//  - is_start[j] = hi[j] || ((j - a(j)) % 8 == 0), a(j)=max(last hi < j, 0)
//  - size at start j = min(first d in [1,8) with hi[j+d], else 8, S-j)
//
// Round-6: keep the round-5 fused single-launch structure (RELAXED tagged
// lookback — passed, cheap), fix the emit phase (the measured ~15us gap):
//  (a) tokens staged in LDS (2048+8) at phase A -> emit does LDS reads, not
//      ~60 scalar global loads/thread;
//  (b) pass-2 rank-order emit: phase C only scatters local_rank->start_pos
//      (ushort) into LDS; then threads walk rows BY RANK (lr=t; lr+=256) so
//      consecutive lanes write consecutive 32B rows -> dense coalesced
//      int4 stores (round-5 emit had ~224B lane stride = 64 lines/instr).
// Data note: tokens iid uniform(8) -> ~90% of positions are hi -> ntot~14.8K
// rows/seq; emit+tail writes ~19MB total and should be write-BW-bound.

#define S_LEN 16384
#define BATCH 32
#define NCH 8
#define CHUNK 2048
#define NTH 256
#define PPT 8
#define MAX_PS 8
#define MAGIC 0x5A17ULL

__global__ __launch_bounds__(NTH)
void fused_kernel(const int* __restrict__ tokens,
                  int* __restrict__ patches,   // [B, S, 8]
                  int* __restrict__ offsets,   // [B, S]
                  int* __restrict__ nout,      // [B]
                  int* __restrict__ cu,        // [B+1]
                  unsigned long long* __restrict__ sumPub,   // [B*NCH]
                  unsigned long long* __restrict__ ntotPub)  // [B]
{
    const int blk = blockIdx.x;
    const int b = blk >> 3, c = blk & 7;
    const int t = threadIdx.x;
    const int lane = t & 63, wv = t >> 6;
    const int cs = c * CHUNK;
    const int pl = t * PPT;          // local position of this thread's first elem
    const int p = cs + pl;           // global position
    const int* __restrict__ seq = tokens + (size_t)b * S_LEN;
    int* __restrict__ pat = patches + (size_t)b * S_LEN * MAX_PS;
    int* __restrict__ off = offsets + (size_t)b * S_LEN;

    __shared__ int tok_s[CHUNK + 8];       // chunk tokens + 8 next-chunk spill
    __shared__ unsigned short rs_s[CHUNK]; // local rank -> local start pos
    __shared__ unsigned char bs[NTH];
    __shared__ unsigned hw[65];            // 64 words chunk hi bits + lookahead word
    __shared__ int partMax[4], partSum[4], red[8];
    __shared__ int anch_s, base_s, ctot_s, ntot_s;

    // ---- Phase A: load tokens, stage to LDS, hi bits ----
    int v[12];
    int4 a4 = *(const int4*)(seq + p);
    int4 b4 = *(const int4*)(seq + p + 4);
    int4 c4 = make_int4(0, 0, 0, 0);
    if (p + 8 < S_LEN) c4 = *(const int4*)(seq + p + 8);
    v[0]=a4.x; v[1]=a4.y; v[2]=a4.z; v[3]=a4.w;
    v[4]=b4.x; v[5]=b4.y; v[6]=b4.z; v[7]=b4.w;
    v[8]=c4.x; v[9]=c4.y; v[10]=c4.z; v[11]=c4.w;

    *(int4*)&tok_s[pl]     = a4;
    *(int4*)&tok_s[pl + 4] = b4;
    if (t < 8) {
        int j2 = cs + CHUNK + t;
        tok_s[CHUNK + t] = (j2 < S_LEN) ? seq[j2] : 0;
    }

    unsigned hb = 0;
    int llh = -1, ffh = S_LEN;
#pragma unroll
    for (int k = 0; k < PPT; ++k) {
        int j = p + k;
        int nv = min(4, S_LEN - j);
        unsigned m = 0;
#pragma unroll
        for (int i = 0; i < 4; ++i) if (i < nv) m |= 1u << (v[k + i] & 31);
        int h = (__popc(m) >= 3) ? 1 : 0;
        hb |= (unsigned)h << k;
        if (h) { llh = j; if (ffh == S_LEN) ffh = j; }
    }
    bs[t] = (unsigned char)hb;

    // lookahead hi bits for positions [cs+CHUNK, cs+CHUNK+7)
    int eh = 0;
    if (t < 7) {
        int j = cs + CHUNK + t;
        if (j < S_LEN) {
            int nv = min(4, S_LEN - j);
            unsigned m = 0;
            for (int i = 0; i < 4; ++i) if (i < nv) m |= 1u << (seq[j + i] & 31);
            eh = (__popc(m) >= 3) ? 1 : 0;
        }
    }
    unsigned long long bal = __ballot(eh);
    if (t == 0) hw[64] = (unsigned)(bal & 0x7f);

    // wave reductions (max llh, min ffh) + exclusive-prefix-max of llh
    int mx = llh, mn = ffh;
#pragma unroll
    for (int d = 32; d >= 1; d >>= 1) {
        mx = max(mx, __shfl_down(mx, d));
        mn = min(mn, __shfl_down(mn, d));
    }
    if (lane == 0) { red[wv] = mx; red[4 + wv] = mn; }
    int incl = llh;
#pragma unroll
    for (int d = 1; d < 64; d <<= 1) {
        int u = __shfl_up(incl, d);
        if (lane >= d) incl = max(incl, u);
    }
    if (lane == 63) partMax[wv] = incl;
    __syncthreads();                                    // (1)

    if (t < 64)
        hw[t] = (unsigned)bs[4*t] | ((unsigned)bs[4*t+1] << 8) |
                ((unsigned)bs[4*t+2] << 16) | ((unsigned)bs[4*t+3] << 24);

    int runx = __shfl_up(incl, 1);
    if (lane == 0) runx = -1;
    for (int w = 0; w < wv; ++w) runx = max(runx, partMax[w]);

    // internal start count A (anchor-independent)
    {
        int run = runx, ci = 0;
#pragma unroll
        for (int k = 0; k < PPT; ++k) {
            int j = p + k;
            int h = (hb >> k) & 1;
            int is = h | ((run >= 0) & (((j - run) & 7) == 0));
            ci += is;
            if (h) run = j;
        }
        int s = ci;
#pragma unroll
        for (int d = 32; d >= 1; d >>= 1) s += __shfl_down(s, d);
        if (lane == 0) partSum[wv] = s;
    }
    __syncthreads();                                    // (2)

    if (t == 0) {
        int lastHi = max(max(red[0], red[1]), max(red[2], red[3]));
        int fh     = min(min(red[4], red[5]), min(red[6], red[7]));
        int fhl    = min(fh - cs, CHUNK);
        int A      = partSum[0] + partSum[1] + partSum[2] + partSum[3];
        unsigned long long pk = (MAGIC << 48)
                              | ((unsigned long long)(unsigned)(lastHi + 1) << 32)
                              | ((unsigned long long)(unsigned)fhl << 16)
                              | (unsigned long long)(unsigned)A;
        __hip_atomic_store(&sumPub[blk], pk, __ATOMIC_RELAXED, __HIP_MEMORY_SCOPE_AGENT);
    }

    // ---- Phase B: lookback (RELAXED; payload packed with MAGIC tag) ----
    int lh_l = 0, fl_l = 0, A_l = 0;
    if (wv == 0 && lane < c) {
        unsigned long long sv;
        for (;;) {
            sv = __hip_atomic_load(&sumPub[b*NCH + lane], __ATOMIC_RELAXED, __HIP_MEMORY_SCOPE_AGENT);
            if ((sv >> 48) == MAGIC) break;
            __builtin_amdgcn_s_sleep(1);
        }
        lh_l = (int)((sv >> 32) & 0xffff) - 1;
        fl_l = (int)((sv >> 16) & 0xffff);
        A_l  = (int)(sv & 0xffff);
    }
    if (wv == 0) {
        int anchor = -1, base = 0;
        for (int cp = 0; cp < c; ++cp) {
            int lh = __shfl(lh_l, cp);
            int fl = __shfl(fl_l, cp);
            int Ap = __shfl(A_l, cp);
            int lo = cp * CHUNK, hi2 = lo + fl;
            int a = max(anchor, 0);
            base += ((hi2 - a + 7) >> 3) - ((lo - a + 7) >> 3) + Ap;
            if (lh >= 0) anchor = lh;
        }
        if (lane == 0) { anch_s = anchor; base_s = base; }
    }
    __syncthreads();                                    // (3)

    // ---- Phase C: flags + local ranks ----
    int run = max(runx, anch_s);
    unsigned fb = 0;
    int cl = 0;
#pragma unroll
    for (int k = 0; k < PPT; ++k) {
        int j = p + k;
        int h = (hb >> k) & 1;
        int a = max(run, 0);
        int is = h | (((j - a) & 7) == 0);
        fb |= (unsigned)is << k;
        cl += is;
        if (h) run = j;
    }
    int sincl = cl;
#pragma unroll
    for (int d = 1; d < 64; d <<= 1) {
        int u = __shfl_up(sincl, d);
        if (lane >= d) sincl += u;
    }
    if (lane == 63) partSum[wv] = sincl;                // reuse after barrier (3)
    __syncthreads();                                    // (4)
    int sexcl = __shfl_up(sincl, 1);
    if (lane == 0) sexcl = 0;
    int lr = sexcl;                                     // local (chunk) rank
    for (int w = 0; w < wv; ++w) lr += partSum[w];

    if (t == 0) {
        int ctot = partSum[0] + partSum[1] + partSum[2] + partSum[3];
        ctot_s = ctot;
        if (c == NCH - 1) {
            int ntot = base_s + ctot;
            ntot_s = ntot;
            nout[b] = ntot;
            __hip_atomic_store(&ntotPub[b], (MAGIC << 48) | (unsigned long long)(unsigned)ntot,
                               __ATOMIC_RELAXED, __HIP_MEMORY_SCOPE_AGENT);
        }
    }

    // scatter local rank -> local start position
    {
        int q = lr;
#pragma unroll
        for (int k = 0; k < PPT; ++k) {
            if ((fb >> k) & 1u) rs_s[q++] = (unsigned short)(pl + k);
        }
    }
    __syncthreads();                                    // (5)

    // ---- Pass 2: rank-order emit (dense coalesced stores) ----
    const int base = base_s, ctot = ctot_s;
    for (int r2 = t; r2 < ctot; r2 += NTH) {
        int pos = rs_s[r2];
        int j = cs + pos;
        int size = 8;
#pragma unroll
        for (int d = 1; d <= 7; ++d) {
            int bb = pos + d;
            if ((hw[bb >> 5] >> (bb & 31)) & 1u) { size = d; break; }
        }
        size = min(size, S_LEN - j);
        int vals[8];
#pragma unroll
        for (int q = 0; q < 8; ++q) vals[q] = (q < size) ? tok_s[pos + q] : 0;
        off[base + r2] = j;
        int4* dst = (int4*)(pat + (size_t)(base + r2) * MAX_PS);
        dst[0] = make_int4(vals[0], vals[1], vals[2], vals[3]);
        dst[1] = make_int4(vals[4], vals[5], vals[6], vals[7]);
    }

    // ---- tail fill (block c==7 of each sequence) ----
    if (c == NCH - 1) {
        const int4 z = make_int4(0, 0, 0, 0);
        for (int r2 = ntot_s + t; r2 < S_LEN; r2 += NTH) {
            off[r2] = -1;
            int4* dst = (int4*)(pat + (size_t)r2 * MAX_PS);
            dst[0] = z;
            dst[1] = z;
        }
    }

    // ---- cu_seqlens by block (0,0), wave 0 ----
    if (b == 0 && c == 0 && wv == 0) {
        int nv2 = 0;
        if (lane < BATCH) {
            unsigned long long sv;
            for (;;) {
                sv = __hip_atomic_load(&ntotPub[lane], __ATOMIC_RELAXED, __HIP_MEMORY_SCOPE_AGENT);
                if ((sv >> 48) == MAGIC) break;
                __builtin_amdgcn_s_sleep(1);
            }
            nv2 = (int)(sv & 0xffff);
        }
        int sc2 = nv2;
#pragma unroll
        for (int d = 1; d < 32; d <<= 1) {
            int u = __shfl_up(sc2, d);
            if (lane >= d) sc2 += u;
        }
        if (lane < BATCH) cu[lane + 1] = sc2;
        if (lane == 0) cu[0] = 0;
    }
}

extern "C" void kernel_launch(void* const* d_in, const int* in_sizes, int n_in,
                              void* d_out, int out_size, void* d_ws, size_t ws_size,
                              hipStream_t stream)
{
    const int* tokens = (const int*)d_in[0];
    int* out = (int*)d_out;
    // Output layout (int32, return order):
    //   patches [32,16384,8] -> 4,194,304 ; offsets [32,16384] -> 524,288 ;
    //   n [32] ; cu_seqlens [33]
    int* patches = out;
    int* offsets = patches + (size_t)BATCH * S_LEN * MAX_PS;
    int* nout    = offsets + (size_t)BATCH * S_LEN;
    int* cu      = nout + BATCH;

    unsigned long long* sumPub  = (unsigned long long*)d_ws;            // 2 KB
    unsigned long long* ntotPub = sumPub + BATCH * NCH;                 // 256 B

    fused_kernel<<<dim3(BATCH * NCH), dim3(NTH), 0, stream>>>(
        tokens, patches, offsets, nout, cu, sumPub, ntotPub);
}

// Round 8
// 71.889 us; speedup vs baseline: 1.1852x; 1.0242x over previous
//
#include <hip/hip_runtime.h>

// AdaptivePatcher: B=32 seqs of S=16384 int32 tokens (0..7).
// MIN_PS=1, MAX_PS=8, LOOKAHEAD=4, THRESH=1.2 bits, PAD=0.
//
// Math (verified rounds 2-6, absmax=0):
//  - hi[p] <=> distinct-count of (masked) 4-window >= 3
//  - is_start[j] = hi[j] || ((j - a(j)) % 8 == 0), a(j)=max(last hi < j, 0)
//  - size at start j = min(first d in [1,8) with hi[j+d], else 8, S-j)
//
// Round-8 = round-7 (NTH 256->1024 for 4x TLP: round-6 ran 1 wave/SIMD,
// nothing hid LDS/store latency) + alignment fix: with PPT=2 the old
// int4 load at seq[2t] was only 8-byte aligned for odd t (UB / possible
// fault). Now 3x int2 loads, all naturally aligned. Lookback (RELAXED
// tagged publishes), LDS token staging, rank-order coalesced emit are
// unchanged from the round-6 kernel that passed absmax=0.

#define S_LEN 16384
#define BATCH 32
#define NCH 8
#define CHUNK 2048
#define NTH 1024
#define PPT 2
#define NWV (NTH / 64)          // 16 waves
#define MAX_PS 8
#define MAGIC 0x5A17ULL

__global__ __launch_bounds__(NTH)
void fused_kernel(const int* __restrict__ tokens,
                  int* __restrict__ patches,   // [B, S, 8]
                  int* __restrict__ offsets,   // [B, S]
                  int* __restrict__ nout,      // [B]
                  int* __restrict__ cu,        // [B+1]
                  unsigned long long* __restrict__ sumPub,   // [B*NCH]
                  unsigned long long* __restrict__ ntotPub)  // [B]
{
    const int blk = blockIdx.x;
    const int b = blk >> 3, c = blk & 7;
    const int t = threadIdx.x;
    const int lane = t & 63, wv = t >> 6;
    const int cs = c * CHUNK;
    const int pl = t * PPT;          // local position (0..2046, even)
    const int p = cs + pl;           // global position
    const int* __restrict__ seq = tokens + (size_t)b * S_LEN;
    int* __restrict__ pat = patches + (size_t)b * S_LEN * MAX_PS;
    int* __restrict__ off = offsets + (size_t)b * S_LEN;

    __shared__ int tok_s[CHUNK + 8];       // chunk tokens + 8 next-chunk spill
    __shared__ unsigned short rs_s[CHUNK]; // local rank -> local start pos
    __shared__ unsigned char bs[NTH];      // 2 hi bits per thread
    __shared__ unsigned hw[65];            // 64 words chunk hi bits + lookahead
    __shared__ int partMax[NWV], partSum[NWV], red[2 * NWV];
    __shared__ int anch_s, base_s, ctot_s, ntot_s;

    // ---- Phase A: load 6 tokens (2 own + 4 lookahead), stage to LDS ----
    // int2 loads only: byte offsets 8t/8t+8/8t+16 are all 8-aligned.
    int v[6];
    if (p + 5 < S_LEN) {
        int2 a2 = *(const int2*)(seq + p);
        int2 b2 = *(const int2*)(seq + p + 2);
        int2 c2 = *(const int2*)(seq + p + 4);
        v[0]=a2.x; v[1]=a2.y; v[2]=b2.x; v[3]=b2.y; v[4]=c2.x; v[5]=c2.y;
    } else {
#pragma unroll
        for (int i = 0; i < 6; ++i) v[i] = (p + i < S_LEN) ? seq[p + i] : 0;
    }
    *(int2*)&tok_s[pl] = make_int2(v[0], v[1]);
    if (t < 8) {
        int j2 = cs + CHUNK + t;
        tok_s[CHUNK + t] = (j2 < S_LEN) ? seq[j2] : 0;
    }

    unsigned hb = 0;
    int llh = -1, ffh = S_LEN;
#pragma unroll
    for (int k = 0; k < PPT; ++k) {
        int j = p + k;
        int nv = min(4, S_LEN - j);
        unsigned m = 0;
#pragma unroll
        for (int i = 0; i < 4; ++i) if (i < nv) m |= 1u << (v[k + i] & 31);
        int h = (__popc(m) >= 3) ? 1 : 0;
        hb |= (unsigned)h << k;
        if (h) { llh = j; if (ffh == S_LEN) ffh = j; }
    }
    bs[t] = (unsigned char)hb;

    // lookahead hi bits for positions [cs+CHUNK, cs+CHUNK+7) (wave 0)
    int eh = 0;
    if (t < 7) {
        int j = cs + CHUNK + t;
        if (j < S_LEN) {
            int nv = min(4, S_LEN - j);
            unsigned m = 0;
            for (int i = 0; i < 4; ++i) if (i < nv) m |= 1u << (seq[j + i] & 31);
            eh = (__popc(m) >= 3) ? 1 : 0;
        }
    }
    unsigned long long bal = __ballot(eh);
    if (t == 0) hw[64] = (unsigned)(bal & 0x7f);

    // wave reductions (max llh, min ffh) + exclusive-prefix-max of llh
    int mx = llh, mn = ffh;
#pragma unroll
    for (int d = 32; d >= 1; d >>= 1) {
        mx = max(mx, __shfl_down(mx, d));
        mn = min(mn, __shfl_down(mn, d));
    }
    if (lane == 0) { red[wv] = mx; red[NWV + wv] = mn; }
    int incl = llh;
#pragma unroll
    for (int d = 1; d < 64; d <<= 1) {
        int u = __shfl_up(incl, d);
        if (lane >= d) incl = max(incl, u);
    }
    if (lane == 63) partMax[wv] = incl;
    __syncthreads();                                    // (1)

    if (t < 64) {
        unsigned w = 0;
#pragma unroll
        for (int i = 0; i < 16; ++i) w |= (unsigned)bs[16 * t + i] << (2 * i);
        hw[t] = w;
    }

    int runx = __shfl_up(incl, 1);
    if (lane == 0) runx = -1;
    for (int w = 0; w < wv; ++w) runx = max(runx, partMax[w]);

    // internal start count A (anchor-independent)
    {
        int run = runx, ci = 0;
#pragma unroll
        for (int k = 0; k < PPT; ++k) {
            int j = p + k;
            int h = (hb >> k) & 1;
            int is = h | ((run >= 0) & (((j - run) & 7) == 0));
            ci += is;
            if (h) run = j;
        }
        int s = ci;
#pragma unroll
        for (int d = 32; d >= 1; d >>= 1) s += __shfl_down(s, d);
        if (lane == 0) partSum[wv] = s;
    }
    __syncthreads();                                    // (2)

    if (t == 0) {
        int lastHi = red[0], fh = red[NWV];
        for (int w = 1; w < NWV; ++w) {
            lastHi = max(lastHi, red[w]);
            fh = min(fh, red[NWV + w]);
        }
        int fhl = min(fh - cs, CHUNK);
        int A = 0;
        for (int w = 0; w < NWV; ++w) A += partSum[w];
        unsigned long long pk = (MAGIC << 48)
                              | ((unsigned long long)(unsigned)(lastHi + 1) << 32)
                              | ((unsigned long long)(unsigned)fhl << 16)
                              | (unsigned long long)(unsigned)A;
        __hip_atomic_store(&sumPub[blk], pk, __ATOMIC_RELAXED, __HIP_MEMORY_SCOPE_AGENT);
    }

    // ---- Phase B: lookback (RELAXED; payload packed with MAGIC tag) ----
    int lh_l = 0, fl_l = 0, A_l = 0;
    if (wv == 0 && lane < c) {
        unsigned long long sv;
        for (;;) {
            sv = __hip_atomic_load(&sumPub[b*NCH + lane], __ATOMIC_RELAXED, __HIP_MEMORY_SCOPE_AGENT);
            if ((sv >> 48) == MAGIC) break;
            __builtin_amdgcn_s_sleep(1);
        }
        lh_l = (int)((sv >> 32) & 0xffff) - 1;
        fl_l = (int)((sv >> 16) & 0xffff);
        A_l  = (int)(sv & 0xffff);
    }
    if (wv == 0) {
        int anchor = -1, base = 0;
        for (int cp = 0; cp < c; ++cp) {
            int lh = __shfl(lh_l, cp);
            int fl = __shfl(fl_l, cp);
            int Ap = __shfl(A_l, cp);
            int lo = cp * CHUNK, hi2 = lo + fl;
            int a = max(anchor, 0);
            base += ((hi2 - a + 7) >> 3) - ((lo - a + 7) >> 3) + Ap;
            if (lh >= 0) anchor = lh;
        }
        if (lane == 0) { anch_s = anchor; base_s = base; }
    }
    __syncthreads();                                    // (3)

    // ---- Phase C: flags + local ranks ----
    int run = max(runx, anch_s);
    unsigned fb = 0;
    int cl = 0;
#pragma unroll
    for (int k = 0; k < PPT; ++k) {
        int j = p + k;
        int h = (hb >> k) & 1;
        int a = max(run, 0);
        int is = h | (((j - a) & 7) == 0);
        fb |= (unsigned)is << k;
        cl += is;
        if (h) run = j;
    }
    int sincl = cl;
#pragma unroll
    for (int d = 1; d < 64; d <<= 1) {
        int u = __shfl_up(sincl, d);
        if (lane >= d) sincl += u;
    }
    if (lane == 63) partSum[wv] = sincl;                // reuse after barrier (3)
    __syncthreads();                                    // (4)
    int sexcl = __shfl_up(sincl, 1);
    if (lane == 0) sexcl = 0;
    int lr = sexcl;                                     // local (chunk) rank
    for (int w = 0; w < wv; ++w) lr += partSum[w];

    if (t == 0) {
        int ctot = 0;
        for (int w = 0; w < NWV; ++w) ctot += partSum[w];
        ctot_s = ctot;
        if (c == NCH - 1) {
            int ntot = base_s + ctot;
            ntot_s = ntot;
            nout[b] = ntot;
            __hip_atomic_store(&ntotPub[b], (MAGIC << 48) | (unsigned long long)(unsigned)ntot,
                               __ATOMIC_RELAXED, __HIP_MEMORY_SCOPE_AGENT);
        }
    }

    // scatter local rank -> local start position
    {
        int q = lr;
#pragma unroll
        for (int k = 0; k < PPT; ++k) {
            if ((fb >> k) & 1u) rs_s[q++] = (unsigned short)(pl + k);
        }
    }
    __syncthreads();                                    // (5)

    // ---- Pass 2: rank-order emit (dense coalesced stores) ----
    const int base = base_s, ctot = ctot_s;
    for (int r2 = t; r2 < ctot; r2 += NTH) {
        int pos = rs_s[r2];
        int j = cs + pos;
        int size = 8;
#pragma unroll
        for (int d = 1; d <= 7; ++d) {
            int bb = pos + d;
            if ((hw[bb >> 5] >> (bb & 31)) & 1u) { size = d; break; }
        }
        size = min(size, S_LEN - j);
        int vals[8];
#pragma unroll
        for (int q = 0; q < 8; ++q) vals[q] = (q < size) ? tok_s[pos + q] : 0;
        off[base + r2] = j;
        int4* dst = (int4*)(pat + (size_t)(base + r2) * MAX_PS);
        dst[0] = make_int4(vals[0], vals[1], vals[2], vals[3]);
        dst[1] = make_int4(vals[4], vals[5], vals[6], vals[7]);
    }

    // ---- tail fill (block c==7 of each sequence) ----
    if (c == NCH - 1) {
        const int4 z = make_int4(0, 0, 0, 0);
        for (int r2 = ntot_s + t; r2 < S_LEN; r2 += NTH) {
            off[r2] = -1;
            int4* dst = (int4*)(pat + (size_t)r2 * MAX_PS);
            dst[0] = z;
            dst[1] = z;
        }
    }

    // ---- cu_seqlens by block (0,0), wave 0 ----
    if (b == 0 && c == 0 && wv == 0) {
        int nv2 = 0;
        if (lane < BATCH) {
            unsigned long long sv;
            for (;;) {
                sv = __hip_atomic_load(&ntotPub[lane], __ATOMIC_RELAXED, __HIP_MEMORY_SCOPE_AGENT);
                if ((sv >> 48) == MAGIC) break;
                __builtin_amdgcn_s_sleep(1);
            }
            nv2 = (int)(sv & 0xffff);
        }
        int sc2 = nv2;
#pragma unroll
        for (int d = 1; d < 32; d <<= 1) {
            int u = __shfl_up(sc2, d);
            if (lane >= d) sc2 += u;
        }
        if (lane < BATCH) cu[lane + 1] = sc2;
        if (lane == 0) cu[0] = 0;
    }
}

extern "C" void kernel_launch(void* const* d_in, const int* in_sizes, int n_in,
                              void* d_out, int out_size, void* d_ws, size_t ws_size,
                              hipStream_t stream)
{
    const int* tokens = (const int*)d_in[0];
    int* out = (int*)d_out;
    // Output layout (int32, return order):
    //   patches [32,16384,8] -> 4,194,304 ; offsets [32,16384] -> 524,288 ;
    //   n [32] ; cu_seqlens [33]
    int* patches = out;
    int* offsets = patches + (size_t)BATCH * S_LEN * MAX_PS;
    int* nout    = offsets + (size_t)BATCH * S_LEN;
    int* cu      = nout + BATCH;

    unsigned long long* sumPub  = (unsigned long long*)d_ws;            // 2 KB
    unsigned long long* ntotPub = sumPub + BATCH * NCH;                 // 256 B

    fused_kernel<<<dim3(BATCH * NCH), dim3(NTH), 0, stream>>>(
        tokens, patches, offsets, nout, cu, sumPub, ntotPub);
}